// Round 16
// baseline (46.730 us; speedup 1.0000x reference)
//
#include <hip/hip_runtime.h>
#include <hip/hip_bf16.h>
#include <math.h>

static constexpr int D        = 128;  // embedding dim
static constexpr int NL       = 64;   // labels in [0,64)
static constexpr int NT       = 64;   // kA tile size
static constexpr int NT2      = 128;  // k3 tile size
static constexpr int LIDX_CAP = 512;  // per-label member capacity (c ~ 64)

typedef __attribute__((ext_vector_type(8))) short  bf16x8;
typedef __attribute__((ext_vector_type(4))) float  f32x4;

__device__ __forceinline__ float wave_reduce_sum(float v) {
  #pragma unroll
  for (int o = 32; o; o >>= 1) v += __shfl_xor(v, o, 64);
  return v;
}

__device__ __forceinline__ float fast_acosh(float x) {  // x >= 1
  float s = __builtin_amdgcn_sqrtf(fmaf(x, x, -1.0f));
  return __logf(x + s);
}

// f32 -> bf16 round-to-nearest-even (bit-level)
__device__ __forceinline__ unsigned short f2b(float x) {
  unsigned int u = __float_as_uint(x);
  unsigned int lsb = (u >> 16) & 1u;
  u += 0x7fffu + lsb;
  return (unsigned short)(u >> 16);
}
__device__ __forceinline__ float b2f(unsigned short u) {
  return __uint_as_float(((unsigned int)u) << 16);
}

// ---------------------------------------------------------------------------
// kA: fused, order-free (unchanged from R11/R13 best).
//  blocks 0..NL-1      : positive pass for label l = bid (self-sufficient).
//  blocks NL..NL+B/4-1 : bf16 precompute + global sq/vv (for k3).
__global__ __launch_bounds__(256) void kA(
    const float* __restrict__ emb, const int* __restrict__ lab,
    unsigned short* __restrict__ bfe, float* __restrict__ sq,
    float* __restrict__ vv, float* __restrict__ hpm,
    int* __restrict__ LC, float* __restrict__ plsum, int B) {
  const int t = threadIdx.x;
  const int bid = blockIdx.x;

  if (bid >= NL) {  // ----- rowstat blocks: bfe + sq + vv ------------------
    int w = t >> 6, lane = t & 63;
    int i = (bid - NL) * 4 + w;
    float2 v = reinterpret_cast<const float2*>(emb + (size_t)i * D)[lane];
    ushort2 bv = { f2b(v.x), f2b(v.y) };
    *reinterpret_cast<ushort2*>(&bfe[(size_t)i * D + 2 * lane]) = bv;
    float s = wave_reduce_sum(v.x * v.x + v.y * v.y);
    if (lane == 0) {
      sq[i] = s;
      vv[i] = 1.41421356237f / fmaxf(1.0f - s, 1e-6f);
    }
    return;
  }

  // ----- positive block for label l ---------------------------------------
  __shared__ unsigned short Al[NT][D + 8];
  __shared__ unsigned short Bl[NT][D + 8];
  __shared__ float rs[NT], rv[NT];
  __shared__ float cs[NT], cv[NT];
  __shared__ int   ridx[NT], cidx[NT];
  __shared__ int   lidx[LIDX_CAP];
  __shared__ int   parr[256];
  __shared__ float red[8];

  const int l = bid;
  const int wid = t >> 6, lane = t & 63;
  const int lr = lane & 15, lg = lane >> 4;

  // member list: strided count -> block scan -> ordered write (deterministic)
  int mc = 0;
  for (int i = t; i < B; i += 256) mc += (lab[i] == l) ? 1 : 0;
  parr[t] = mc;
  __syncthreads();
  for (int off = 1; off < 256; off <<= 1) {
    int v = (t >= off) ? parr[t - off] : 0;
    __syncthreads();
    parr[t] += v;
    __syncthreads();
  }
  const int c = parr[255];
  {
    int myoff = parr[t] - mc;
    for (int i = t; i < B; i += 256) {
      if (lab[i] == l) {
        if (myoff < LIDX_CAP) lidx[myoff] = i;
        ++myoff;
      }
    }
  }
  if (t == 0) { LC[l] = c; if (c == 0) plsum[l] = 0.0f; }
  if (c == 0) return;
  __syncthreads();

  const int  cc_    = min(c, LIDX_CAP);
  const bool validc = (c >= 2) && (c < B);
  float lsum = 0.0f;

  for (int i0 = 0; i0 < cc_; i0 += NT) {
    int ci = min(NT, cc_ - i0);
    __syncthreads();  // previous i-tile fully consumed
    #pragma unroll
    for (int p = 0; p < 4; ++p) {       // 64 rows x 16 chunks of 8 elems
      int idx = t + p * 256;
      int r = idx >> 4, c16 = idx & 15;
      const float* src = emb + (size_t)lidx[i0 + min(r, ci - 1)] * D + c16 * 8;
      float4 a = *reinterpret_cast<const float4*>(src);
      float4 b = *reinterpret_cast<const float4*>(src + 4);
      ushort4 ua = { f2b(a.x), f2b(a.y), f2b(a.z), f2b(a.w) };
      ushort4 ub = { f2b(b.x), f2b(b.y), f2b(b.z), f2b(b.w) };
      *reinterpret_cast<ushort4*>(&Al[r][c16 * 8]) = ua;
      *reinterpret_cast<ushort4*>(&Al[r][c16 * 8 + 4]) = ub;
    }
    __syncthreads();  // Al visible
    {   // in-block row stats from staged bf16: 4 threads per row
      int r = t >> 2, q = t & 3;
      float s = 0.0f;
      #pragma unroll
      for (int i = 0; i < 4; ++i) {
        bf16x8 v8 = *reinterpret_cast<const bf16x8*>(&Al[r][q * 32 + i * 8]);
        #pragma unroll
        for (int j = 0; j < 8; ++j) {
          float x = b2f((unsigned short)v8[j]);
          s = fmaf(x, x, s);
        }
      }
      s += __shfl_xor(s, 1, 64);
      s += __shfl_xor(s, 2, 64);
      if (q == 0) {
        rs[r] = s;
        rv[r] = 1.41421356237f / fmaxf(1.0f - s, 1e-6f);
        ridx[r] = lidx[i0 + min(r, ci - 1)];
      }
    }

    float rmax[4] = {0.0f, 0.0f, 0.0f, 0.0f};

    for (int j0 = 0; j0 < cc_; j0 += NT) {
      int cj = min(NT, cc_ - j0);
      __syncthreads();  // prev Bl consumed; rs writes visible
      #pragma unroll
      for (int p = 0; p < 4; ++p) {
        int idx = t + p * 256;
        int r = idx >> 4, c16 = idx & 15;
        const float* src = emb + (size_t)lidx[j0 + min(r, cj - 1)] * D + c16 * 8;
        float4 a = *reinterpret_cast<const float4*>(src);
        float4 b = *reinterpret_cast<const float4*>(src + 4);
        ushort4 ua = { f2b(a.x), f2b(a.y), f2b(a.z), f2b(a.w) };
        ushort4 ub = { f2b(b.x), f2b(b.y), f2b(b.z), f2b(b.w) };
        *reinterpret_cast<ushort4*>(&Bl[r][c16 * 8]) = ua;
        *reinterpret_cast<ushort4*>(&Bl[r][c16 * 8 + 4]) = ub;
      }
      __syncthreads();  // Bl visible
      {
        int r = t >> 2, q = t & 3;
        float s = 0.0f;
        #pragma unroll
        for (int i = 0; i < 4; ++i) {
          bf16x8 v8 = *reinterpret_cast<const bf16x8*>(&Bl[r][q * 32 + i * 8]);
          #pragma unroll
          for (int j = 0; j < 8; ++j) {
            float x = b2f((unsigned short)v8[j]);
            s = fmaf(x, x, s);
          }
        }
        s += __shfl_xor(s, 1, 64);
        s += __shfl_xor(s, 2, 64);
        if (q == 0) {
          cs[r] = s;
          cv[r] = 1.41421356237f / fmaxf(1.0f - s, 1e-6f);
          cidx[r] = lidx[j0 + min(r, cj - 1)];
        }
      }
      __syncthreads();  // cs/cv visible

      f32x4 dacc[4];
      #pragma unroll
      for (int n = 0; n < 4; ++n) dacc[n] = (f32x4){0.f, 0.f, 0.f, 0.f};
      #pragma unroll
      for (int kk = 0; kk < 4; ++kk) {
        bf16x8 a = *reinterpret_cast<const bf16x8*>(&Al[wid * 16 + lr][kk * 32 + lg * 8]);
        bf16x8 b[4];
        #pragma unroll
        for (int n = 0; n < 4; ++n)
          b[n] = *reinterpret_cast<const bf16x8*>(&Bl[n * 16 + lr][kk * 32 + lg * 8]);
        #pragma unroll
        for (int n = 0; n < 4; ++n)
          dacc[n] = __builtin_amdgcn_mfma_f32_16x16x32_bf16(a, b[n], dacc[n], 0, 0, 0);
      }

      int r0 = wid * 16 + lg * 4;
      #pragma unroll
      for (int n = 0; n < 4; ++n) {
        int ccn = n * 16 + lr;
        float sc = cs[ccn], vcv = cv[ccn];
        int   gj = cidx[ccn];
        #pragma unroll
        for (int g = 0; g < 4; ++g) {
          int rloc = r0 + g;
          if (rloc < ci && ccn < cj && ridx[rloc] != gj) {
            float diff = fmaxf(fmaf(-2.0f, dacc[n][g], rs[rloc] + sc), 0.0f);
            float arg  = fmaf(diff * rv[rloc], vcv, 1.0f);
            float d    = fast_acosh(arg);
            lsum += d;
            rmax[g] = fmaxf(rmax[g], d);
          }
        }
      }
    }

    // per-row max across the 16 lr lanes; write hardest_pos + margin
    int r0 = wid * 16 + lg * 4;
    #pragma unroll
    for (int g = 0; g < 4; ++g) {
      float v = rmax[g];
      v = fmaxf(v, __shfl_xor(v, 1, 64));
      v = fmaxf(v, __shfl_xor(v, 2, 64));
      v = fmaxf(v, __shfl_xor(v, 4, 64));
      v = fmaxf(v, __shfl_xor(v, 8, 64));
      int rloc = r0 + g;
      if (lr == 0 && rloc < ci) {
        float mg = fmaxf(fmaf(2.0f, __builtin_amdgcn_sqrtf(rs[rloc]), 1.0f), 0.1f);
        hpm[ridx[rloc]] = validc ? (v + mg) : -1e30f;
      }
    }
  }

  lsum = wave_reduce_sum(lsum);
  if (lane == 0) red[wid] = lsum;
  __syncthreads();
  if (t == 0) plsum[l] = (red[0] + red[1]) + (red[2] + red[3]);
}

// ---------------------------------------------------------------------------
// k3: negative pass, 128x128 triangular tiles, 512 threads (8 waves, 2x4),
// persistent G=512 blocks with register-prefetch double-buffering.
// Staging arithmetic: 128 rows x 16 bf16x8-chunks = 2048 chunks per tile;
// 512 threads x p<4 = 2048.  pre[0..3]=A chunks, pre[4..7]=B chunks.
__global__ __launch_bounds__(512) void k3_neg(
    const unsigned short* __restrict__ bfe, const int* __restrict__ lab,
    const float* __restrict__ sq, const float* __restrict__ vv,
    const float* __restrict__ hpm,
    float* __restrict__ part, int B, int G) {
  __shared__ unsigned short Al[NT2][D + 8];
  __shared__ unsigned short Bl[NT2][D + 8];
  __shared__ float rs[NT2], rv[NT2], rh[NT2];
  __shared__ float cs[NT2], cv[NT2], ch[NT2];
  __shared__ int   rl[NT2], cl[NT2];
  __shared__ float red[16];

  const int T2 = B / NT2;                 // 32
  const int ntile = T2 * (T2 + 1) / 2;    // 528
  const int t = threadIdx.x;
  const int wid = t >> 6, lane = t & 63;
  const int wr = wid >> 2, wc = wid & 3;  // 2 x 4 wave grid
  const int lr = lane & 15, lg = lane >> 4;
  const int bid = blockIdx.x;

  bf16x8 pre[8];                          // 4 A-chunks + 4 B-chunks
  float ps0 = 0, ps1 = 0, ps2 = 0;
  int   ps3 = 0;
  float nsum = 0.0f, nact = 0.0f;

  auto decode = [&](int tile, int& bi, int& bj) {
    float disc = (float)((2 * T2 + 1) * (2 * T2 + 1) - 8 * tile);
    int b = (int)(((float)(2 * T2 + 1) - __builtin_amdgcn_sqrtf(disc)) * 0.5f);
    b = max(0, min(b, T2 - 1));
    while (b * T2 - b * (b - 1) / 2 > tile) --b;
    while ((b + 1) * T2 - (b + 1) * b / 2 <= tile) ++b;
    bi = b;
    bj = b + (tile - (b * T2 - b * (b - 1) / 2));
  };

  auto load_tile = [&](int bi, int bj) {
    const unsigned short* ab = bfe + (size_t)bi * NT2 * D;
    const unsigned short* bb = bfe + (size_t)bj * NT2 * D;
    #pragma unroll
    for (int p = 0; p < 4; ++p) {
      int idx = t + p * 512;
      int r = idx >> 4, c16 = idx & 15;
      pre[p]     = reinterpret_cast<const bf16x8*>(ab + (size_t)r * D)[c16];
      pre[4 + p] = reinterpret_cast<const bf16x8*>(bb + (size_t)r * D)[c16];
    }
    if (t < NT2) {
      int g = bi * NT2 + t;
      ps0 = sq[g]; ps1 = vv[g]; ps2 = hpm[g]; ps3 = lab[g];
    } else if (t < 2 * NT2) {
      int g = bj * NT2 + (t - NT2);
      ps0 = sq[g]; ps1 = vv[g]; ps2 = hpm[g]; ps3 = lab[g];
    }
  };

  int tile = bid;
  if (tile >= ntile) return;
  int bi, bj;
  decode(tile, bi, bj);
  float next_dsec = (bi == bj) ? 0.0f : 1.0f;
  load_tile(bi, bj);

  while (tile < ntile) {
    const float dsec = next_dsec;
    __syncthreads();            // previous tile's LDS reads complete
    #pragma unroll
    for (int p = 0; p < 4; ++p) {
      int idx = t + p * 512;
      int r = idx >> 4, c16 = idx & 15;
      *reinterpret_cast<bf16x8*>(&Al[r][c16 * 8]) = pre[p];
      *reinterpret_cast<bf16x8*>(&Bl[r][c16 * 8]) = pre[4 + p];
    }
    if (t < NT2) {
      rs[t] = ps0; rv[t] = ps1; rh[t] = ps2; rl[t] = ps3;
    } else if (t < 2 * NT2) {
      int r = t - NT2;
      cs[r] = ps0; cv[r] = ps1; ch[r] = ps2; cl[r] = ps3;
    }
    int tile_next = tile + G;
    if (tile_next < ntile) {
      decode(tile_next, bi, bj);
      next_dsec = (bi == bj) ? 0.0f : 1.0f;
      load_tile(bi, bj);        // issue next tile's loads under compute
    }
    __syncthreads();            // LDS tile visible

    f32x4 dacc[4][2];
    #pragma unroll
    for (int m = 0; m < 4; ++m)
      #pragma unroll
      for (int n = 0; n < 2; ++n) dacc[m][n] = (f32x4){0.f, 0.f, 0.f, 0.f};

    #pragma unroll
    for (int kk = 0; kk < 4; ++kk) {
      bf16x8 a[4], b[2];
      #pragma unroll
      for (int m = 0; m < 4; ++m)
        a[m] = *reinterpret_cast<const bf16x8*>(&Al[wr * 64 + m * 16 + lr][kk * 32 + lg * 8]);
      #pragma unroll
      for (int n = 0; n < 2; ++n)
        b[n] = *reinterpret_cast<const bf16x8*>(&Bl[wc * 32 + n * 16 + lr][kk * 32 + lg * 8]);
      #pragma unroll
      for (int m = 0; m < 4; ++m)
        #pragma unroll
        for (int n = 0; n < 2; ++n)
          dacc[m][n] = __builtin_amdgcn_mfma_f32_16x16x32_bf16(a[m], b[n], dacc[m][n], 0, 0, 0);
    }

    #pragma unroll
    for (int m = 0; m < 4; ++m) {
      int r0 = wr * 64 + m * 16 + lg * 4;
      f32x4 sr = *reinterpret_cast<const f32x4*>(&rs[r0]);
      f32x4 vr = *reinterpret_cast<const f32x4*>(&rv[r0]);
      f32x4 hr = *reinterpret_cast<const f32x4*>(&rh[r0]);
      int4  lm = *reinterpret_cast<const int4*>(&rl[r0]);
      int lmv[4] = { lm.x, lm.y, lm.z, lm.w };
      #pragma unroll
      for (int n = 0; n < 2; ++n) {
        int ccn = wc * 32 + n * 16 + lr;
        float sc = cs[ccn], vcv = cv[ccn], hc = ch[ccn];
        int   lc = cl[ccn];
        #pragma unroll
        for (int g = 0; g < 4; ++g) {
          float diff = fmaxf(fmaf(-2.0f, dacc[m][n][g], sr[g] + sc), 0.0f);
          float arg  = fmaf(diff * vr[g], vcv, 1.0f);
          float d    = fast_acosh(arg);
          float r1   = hr[g] - d;
          float r2   = hc    - d;
          float neg  = (lmv[g] != lc) ? 1.0f : 0.0f;
          nsum += neg * (fmaxf(r1, 0.0f) + dsec * fmaxf(r2, 0.0f));
          nact += neg * ((r1 > 0.0f ? 1.0f : 0.0f) + dsec * (r2 > 0.0f ? 1.0f : 0.0f));
        }
      }
    }
    tile = tile_next;
  }

  nsum = wave_reduce_sum(nsum);
  nact = wave_reduce_sum(nact);
  if (lane == 0) { red[wid] = nsum; red[8 + wid] = nact; }
  __syncthreads();
  if (t == 0) {
    float S = 0.0f, A = 0.0f;
    #pragma unroll
    for (int w = 0; w < 8; ++w) { S += red[w]; A += red[8 + w]; }
    part[2 * bid]     = S;
    part[2 * bid + 1] = A;
  }
}

// ---------------------------------------------------------------------------
// k4: reduce partials + label analytics + finalize (deterministic).
__global__ __launch_bounds__(256) void k4_final(
    const float* __restrict__ part, int G,
    const int* __restrict__ LC, const float* __restrict__ plsum,
    float* __restrict__ out, int B) {
  __shared__ float sl[256], sa[256];
  __shared__ float fin[3];
  int t = threadIdx.x;
  float s = 0.0f, a = 0.0f;
  for (int i = t; i < G; i += 256) {
    s += part[2 * i];
    a += part[2 * i + 1];
  }
  sl[t] = s; sa[t] = a;
  __syncthreads();
  for (int o = 128; o; o >>= 1) {
    if (t < o) { sl[t] += sl[t + o]; sa[t] += sa[t + o]; }
    __syncthreads();
  }
  // label analytics in wave 0 (t < 64)
  if (t < 64) {
    int   c  = LC[t];
    float cf = (float)c;
    float pc = cf * (cf - 1.0f);
    float tr = ((c >= 2) && (c < B)) ? cf * (float)(B - c) : 0.0f;
    float ps = plsum[t];
    pc = wave_reduce_sum(pc);
    tr = wave_reduce_sum(tr);
    ps = wave_reduce_sum(ps);
    if (t == 0) { fin[0] = pc; fin[1] = tr; fin[2] = ps; }
  }
  __syncthreads();
  if (t == 0) {
    float PC = fin[0], TR = fin[1], PS = fin[2];
    float den = fmaxf(TR, 1.0f);
    out[0] = sl[0] / den;                                   // loss
    out[1] = sa[0];                                         // num_active
    out[2] = TR;                                            // total_triplets
    out[3] = sa[0] / den;                                   // active_ratio
    out[4] = (PC > 0.0f) ? PS / fmaxf(PC, 1.0f) : 0.0f;     // mean_distance
  }
}

extern "C" void kernel_launch(void* const* d_in, const int* in_sizes, int n_in,
                              void* d_out, int out_size, void* d_ws, size_t ws_size,
                              hipStream_t stream) {
  const float* emb = (const float*)d_in[0];
  const int*   lab = (const int*)d_in[1];
  int B = in_sizes[1];

  int T2 = B / NT2;
  int ntile = T2 * (T2 + 1) / 2;   // 528 at B=4096
  int G = 512;                     // 2 blocks/CU co-resident; persistent loop
  if (G > ntile) G = ntile;

  // ws: bfe (B*D ushort) | sq[B] | vv[B] | hpm[B] | LC[NL](int) | plsum[NL] | part[2*G]
  unsigned short* bfe = (unsigned short*)d_ws;
  float* sq    = (float*)(bfe + (size_t)B * D);
  float* vv    = sq + B;
  float* hpm   = vv + B;
  int*   LC    = (int*)(hpm + B);
  float* plsum = (float*)(LC + NL);
  float* part  = plsum + NL;

  kA<<<NL + B / 4, 256, 0, stream>>>(emb, lab, bfe, sq, vv, hpm, LC, plsum, B);
  k3_neg<<<G, 512, 0, stream>>>(bfe, lab, sq, vv, hpm, part, B, G);
  k4_final<<<1, 256, 0, stream>>>(part, G, LC, plsum, (float*)d_out, B);
}

// Round 17
// 44.029 us; speedup vs baseline: 1.0614x; 1.0614x over previous
//
#include <hip/hip_runtime.h>
#include <hip/hip_bf16.h>
#include <math.h>

static constexpr int D        = 128;  // embedding dim
static constexpr int NL       = 64;   // labels in [0,64)
static constexpr int NT       = 64;   // kA tile size
static constexpr int NT2      = 128;  // k3 tile size
static constexpr int LIDX_CAP = 512;  // per-label member capacity (c ~ 64)

typedef __attribute__((ext_vector_type(8))) short  bf16x8;
typedef __attribute__((ext_vector_type(4))) float  f32x4;

__device__ __forceinline__ float wave_reduce_sum(float v) {
  #pragma unroll
  for (int o = 32; o; o >>= 1) v += __shfl_xor(v, o, 64);
  return v;
}

__device__ __forceinline__ float fast_acosh(float x) {  // x >= 1
  float s = __builtin_amdgcn_sqrtf(fmaf(x, x, -1.0f));
  return __logf(x + s);
}

// f32 -> bf16 round-to-nearest-even (bit-level)
__device__ __forceinline__ unsigned short f2b(float x) {
  unsigned int u = __float_as_uint(x);
  unsigned int lsb = (u >> 16) & 1u;
  u += 0x7fffu + lsb;
  return (unsigned short)(u >> 16);
}
__device__ __forceinline__ float b2f(unsigned short u) {
  return __uint_as_float(((unsigned int)u) << 16);
}

// ---------------------------------------------------------------------------
// kA: fused, order-free.
//  blocks 0..NL-1      : positive pass for label l = bid (self-sufficient).
//  blocks NL..NL+B/4-1 : bf16 precompute + global sq/vv (for k3).
__global__ __launch_bounds__(256) void kA(
    const float* __restrict__ emb, const int* __restrict__ lab,
    unsigned short* __restrict__ bfe, float* __restrict__ sq,
    float* __restrict__ vv, float* __restrict__ hpm,
    int* __restrict__ LC, float* __restrict__ plsum, int B) {
  const int t = threadIdx.x;
  const int bid = blockIdx.x;

  if (bid >= NL) {  // ----- rowstat blocks: bfe + sq + vv ------------------
    int w = t >> 6, lane = t & 63;
    int i = (bid - NL) * 4 + w;
    float2 v = reinterpret_cast<const float2*>(emb + (size_t)i * D)[lane];
    ushort2 bv = { f2b(v.x), f2b(v.y) };
    *reinterpret_cast<ushort2*>(&bfe[(size_t)i * D + 2 * lane]) = bv;
    float s = wave_reduce_sum(v.x * v.x + v.y * v.y);
    if (lane == 0) {
      sq[i] = s;
      vv[i] = 1.41421356237f / fmaxf(1.0f - s, 1e-6f);
    }
    return;
  }

  // ----- positive block for label l ---------------------------------------
  __shared__ unsigned short Al[NT][D + 8];
  __shared__ unsigned short Bl[NT][D + 8];
  __shared__ float rs[NT], rv[NT];
  __shared__ float cs[NT], cv[NT];
  __shared__ int   ridx[NT], cidx[NT];
  __shared__ int   lidx[LIDX_CAP];
  __shared__ int   parr[256];
  __shared__ float red[8];

  const int l = bid;
  const int wid = t >> 6, lane = t & 63;
  const int lr = lane & 15, lg = lane >> 4;

  // member list: strided count -> block scan -> ordered write (deterministic)
  int mc = 0;
  for (int i = t; i < B; i += 256) mc += (lab[i] == l) ? 1 : 0;
  parr[t] = mc;
  __syncthreads();
  for (int off = 1; off < 256; off <<= 1) {
    int v = (t >= off) ? parr[t - off] : 0;
    __syncthreads();
    parr[t] += v;
    __syncthreads();
  }
  const int c = parr[255];
  {
    int myoff = parr[t] - mc;
    for (int i = t; i < B; i += 256) {
      if (lab[i] == l) {
        if (myoff < LIDX_CAP) lidx[myoff] = i;
        ++myoff;
      }
    }
  }
  if (t == 0) { LC[l] = c; if (c == 0) plsum[l] = 0.0f; }
  if (c == 0) return;
  __syncthreads();

  const int  cc_    = min(c, LIDX_CAP);
  const bool validc = (c >= 2) && (c < B);
  float lsum = 0.0f;

  for (int i0 = 0; i0 < cc_; i0 += NT) {
    int ci = min(NT, cc_ - i0);
    __syncthreads();  // previous i-tile fully consumed
    #pragma unroll
    for (int p = 0; p < 4; ++p) {       // 64 rows x 16 chunks of 8 elems
      int idx = t + p * 256;
      int r = idx >> 4, c16 = idx & 15;
      const float* src = emb + (size_t)lidx[i0 + min(r, ci - 1)] * D + c16 * 8;
      float4 a = *reinterpret_cast<const float4*>(src);
      float4 b = *reinterpret_cast<const float4*>(src + 4);
      ushort4 ua = { f2b(a.x), f2b(a.y), f2b(a.z), f2b(a.w) };
      ushort4 ub = { f2b(b.x), f2b(b.y), f2b(b.z), f2b(b.w) };
      *reinterpret_cast<ushort4*>(&Al[r][c16 * 8]) = ua;
      *reinterpret_cast<ushort4*>(&Al[r][c16 * 8 + 4]) = ub;
    }
    __syncthreads();  // Al visible
    {   // in-block row stats from staged bf16: 4 threads per row
      int r = t >> 2, q = t & 3;
      float s = 0.0f;
      #pragma unroll
      for (int i = 0; i < 4; ++i) {
        bf16x8 v8 = *reinterpret_cast<const bf16x8*>(&Al[r][q * 32 + i * 8]);
        #pragma unroll
        for (int j = 0; j < 8; ++j) {
          float x = b2f((unsigned short)v8[j]);
          s = fmaf(x, x, s);
        }
      }
      s += __shfl_xor(s, 1, 64);
      s += __shfl_xor(s, 2, 64);
      if (q == 0) {
        rs[r] = s;
        rv[r] = 1.41421356237f / fmaxf(1.0f - s, 1e-6f);
        ridx[r] = lidx[i0 + min(r, ci - 1)];
      }
    }

    float rmax[4] = {0.0f, 0.0f, 0.0f, 0.0f};

    for (int j0 = 0; j0 < cc_; j0 += NT) {
      int cj = min(NT, cc_ - j0);
      __syncthreads();  // prev Bl consumed; rs writes visible
      #pragma unroll
      for (int p = 0; p < 4; ++p) {
        int idx = t + p * 256;
        int r = idx >> 4, c16 = idx & 15;
        const float* src = emb + (size_t)lidx[j0 + min(r, cj - 1)] * D + c16 * 8;
        float4 a = *reinterpret_cast<const float4*>(src);
        float4 b = *reinterpret_cast<const float4*>(src + 4);
        ushort4 ua = { f2b(a.x), f2b(a.y), f2b(a.z), f2b(a.w) };
        ushort4 ub = { f2b(b.x), f2b(b.y), f2b(b.z), f2b(b.w) };
        *reinterpret_cast<ushort4*>(&Bl[r][c16 * 8]) = ua;
        *reinterpret_cast<ushort4*>(&Bl[r][c16 * 8 + 4]) = ub;
      }
      __syncthreads();  // Bl visible
      {
        int r = t >> 2, q = t & 3;
        float s = 0.0f;
        #pragma unroll
        for (int i = 0; i < 4; ++i) {
          bf16x8 v8 = *reinterpret_cast<const bf16x8*>(&Bl[r][q * 32 + i * 8]);
          #pragma unroll
          for (int j = 0; j < 8; ++j) {
            float x = b2f((unsigned short)v8[j]);
            s = fmaf(x, x, s);
          }
        }
        s += __shfl_xor(s, 1, 64);
        s += __shfl_xor(s, 2, 64);
        if (q == 0) {
          cs[r] = s;
          cv[r] = 1.41421356237f / fmaxf(1.0f - s, 1e-6f);
          cidx[r] = lidx[j0 + min(r, cj - 1)];
        }
      }
      __syncthreads();  // cs/cv visible

      f32x4 dacc[4];
      #pragma unroll
      for (int n = 0; n < 4; ++n) dacc[n] = (f32x4){0.f, 0.f, 0.f, 0.f};
      #pragma unroll
      for (int kk = 0; kk < 4; ++kk) {
        bf16x8 a = *reinterpret_cast<const bf16x8*>(&Al[wid * 16 + lr][kk * 32 + lg * 8]);
        bf16x8 b[4];
        #pragma unroll
        for (int n = 0; n < 4; ++n)
          b[n] = *reinterpret_cast<const bf16x8*>(&Bl[n * 16 + lr][kk * 32 + lg * 8]);
        #pragma unroll
        for (int n = 0; n < 4; ++n)
          dacc[n] = __builtin_amdgcn_mfma_f32_16x16x32_bf16(a, b[n], dacc[n], 0, 0, 0);
      }

      int r0 = wid * 16 + lg * 4;
      #pragma unroll
      for (int n = 0; n < 4; ++n) {
        int ccn = n * 16 + lr;
        float sc = cs[ccn], vcv = cv[ccn];
        int   gj = cidx[ccn];
        #pragma unroll
        for (int g = 0; g < 4; ++g) {
          int rloc = r0 + g;
          if (rloc < ci && ccn < cj && ridx[rloc] != gj) {
            float diff = fmaxf(fmaf(-2.0f, dacc[n][g], rs[rloc] + sc), 0.0f);
            float arg  = fmaf(diff * rv[rloc], vcv, 1.0f);
            float d    = fast_acosh(arg);
            lsum += d;
            rmax[g] = fmaxf(rmax[g], d);
          }
        }
      }
    }

    // per-row max across the 16 lr lanes; write hardest_pos + margin
    int r0 = wid * 16 + lg * 4;
    #pragma unroll
    for (int g = 0; g < 4; ++g) {
      float v = rmax[g];
      v = fmaxf(v, __shfl_xor(v, 1, 64));
      v = fmaxf(v, __shfl_xor(v, 2, 64));
      v = fmaxf(v, __shfl_xor(v, 4, 64));
      v = fmaxf(v, __shfl_xor(v, 8, 64));
      int rloc = r0 + g;
      if (lr == 0 && rloc < ci) {
        float mg = fmaxf(fmaf(2.0f, __builtin_amdgcn_sqrtf(rs[rloc]), 1.0f), 0.1f);
        hpm[ridx[rloc]] = validc ? (v + mg) : -1e30f;
      }
    }
  }

  lsum = wave_reduce_sum(lsum);
  if (lane == 0) red[wid] = lsum;
  __syncthreads();
  if (t == 0) plsum[l] = (red[0] + red[1]) + (red[2] + red[3]);
}

// ---------------------------------------------------------------------------
// k3: negative pass, 128x128 triangular tiles, 512 threads (8 waves, 2x4),
// coalesced bf16 staging from bfe. Flat one-shot grid (528 blocks) — the
// persistent/prefetch variant measured slower (R16).
__global__ __launch_bounds__(512) void k3_neg(
    const unsigned short* __restrict__ bfe, const int* __restrict__ lab,
    const float* __restrict__ sq, const float* __restrict__ vv,
    const float* __restrict__ hpm,
    float* __restrict__ part, int B) {
  __shared__ unsigned short Al[NT2][D + 8];
  __shared__ unsigned short Bl[NT2][D + 8];
  __shared__ float rs[NT2], rv[NT2], rh[NT2];
  __shared__ float cs[NT2], cv[NT2], ch[NT2];
  __shared__ int   rl[NT2], cl[NT2];
  __shared__ float red[16];

  const int T2 = B / NT2;                 // 32
  const int t = threadIdx.x;
  const int wid = t >> 6, lane = t & 63;
  const int wr = wid >> 2, wc = wid & 3;  // 2 x 4 wave grid
  const int lr = lane & 15, lg = lane >> 4;
  const int bid = blockIdx.x;

  // triangular decode
  float disc = (float)((2 * T2 + 1) * (2 * T2 + 1) - 8 * bid);
  int bi = (int)(((float)(2 * T2 + 1) - __builtin_amdgcn_sqrtf(disc)) * 0.5f);
  bi = max(0, min(bi, T2 - 1));
  while (bi * T2 - bi * (bi - 1) / 2 > bid) --bi;
  while ((bi + 1) * T2 - (bi + 1) * bi / 2 <= bid) ++bi;
  int bj = bi + (bid - (bi * T2 - bi * (bi - 1) / 2));
  const float dsec = (bi == bj) ? 0.0f : 1.0f;

  // coalesced staging: 128 rows x 16 chunks of 16B per tile, 512 threads
  const unsigned short* ab = bfe + (size_t)bi * NT2 * D;
  const unsigned short* bb = bfe + (size_t)bj * NT2 * D;
  #pragma unroll
  for (int p = 0; p < 4; ++p) {
    int idx = t + p * 512;
    int r = idx >> 4, c16 = idx & 15;
    bf16x8 va = reinterpret_cast<const bf16x8*>(ab + (size_t)r * D)[c16];
    bf16x8 vb = reinterpret_cast<const bf16x8*>(bb + (size_t)r * D)[c16];
    *reinterpret_cast<bf16x8*>(&Al[r][c16 * 8]) = va;
    *reinterpret_cast<bf16x8*>(&Bl[r][c16 * 8]) = vb;
  }
  if (t < NT2) {
    int g = bi * NT2 + t;
    rs[t] = sq[g]; rv[t] = vv[g]; rh[t] = hpm[g]; rl[t] = lab[g];
  } else if (t < 2 * NT2) {
    int r = t - NT2, g = bj * NT2 + r;
    cs[r] = sq[g]; cv[r] = vv[g]; ch[r] = hpm[g]; cl[r] = lab[g];
  }
  __syncthreads();

  // wave (wr,wc) owns rows [wr*64,+64) x cols [wc*32,+32): 4x2 fragments
  f32x4 dacc[4][2];
  #pragma unroll
  for (int m = 0; m < 4; ++m)
    #pragma unroll
    for (int n = 0; n < 2; ++n) dacc[m][n] = (f32x4){0.f, 0.f, 0.f, 0.f};

  #pragma unroll
  for (int kk = 0; kk < 4; ++kk) {
    bf16x8 a[4], b[2];
    #pragma unroll
    for (int m = 0; m < 4; ++m)
      a[m] = *reinterpret_cast<const bf16x8*>(&Al[wr * 64 + m * 16 + lr][kk * 32 + lg * 8]);
    #pragma unroll
    for (int n = 0; n < 2; ++n)
      b[n] = *reinterpret_cast<const bf16x8*>(&Bl[wc * 32 + n * 16 + lr][kk * 32 + lg * 8]);
    #pragma unroll
    for (int m = 0; m < 4; ++m)
      #pragma unroll
      for (int n = 0; n < 2; ++n)
        dacc[m][n] = __builtin_amdgcn_mfma_f32_16x16x32_bf16(a[m], b[n], dacc[m][n], 0, 0, 0);
  }

  float nsum = 0.0f, nact = 0.0f;
  #pragma unroll
  for (int m = 0; m < 4; ++m) {
    int r0 = wr * 64 + m * 16 + lg * 4;
    f32x4 sr = *reinterpret_cast<const f32x4*>(&rs[r0]);
    f32x4 vr = *reinterpret_cast<const f32x4*>(&rv[r0]);
    f32x4 hr = *reinterpret_cast<const f32x4*>(&rh[r0]);
    int4  lm = *reinterpret_cast<const int4*>(&rl[r0]);
    int lmv[4] = { lm.x, lm.y, lm.z, lm.w };
    #pragma unroll
    for (int n = 0; n < 2; ++n) {
      int ccn = wc * 32 + n * 16 + lr;
      float sc = cs[ccn], vcv = cv[ccn], hc = ch[ccn];
      int   lc = cl[ccn];
      #pragma unroll
      for (int g = 0; g < 4; ++g) {
        float diff = fmaxf(fmaf(-2.0f, dacc[m][n][g], sr[g] + sc), 0.0f);
        float arg  = fmaf(diff * vr[g], vcv, 1.0f);
        float d    = fast_acosh(arg);
        float r1   = hr[g] - d;
        float r2   = hc    - d;
        float neg  = (lmv[g] != lc) ? 1.0f : 0.0f;
        nsum += neg * (fmaxf(r1, 0.0f) + dsec * fmaxf(r2, 0.0f));
        nact += neg * ((r1 > 0.0f ? 1.0f : 0.0f) + dsec * (r2 > 0.0f ? 1.0f : 0.0f));
      }
    }
  }

  nsum = wave_reduce_sum(nsum);
  nact = wave_reduce_sum(nact);
  if (lane == 0) { red[wid] = nsum; red[8 + wid] = nact; }
  __syncthreads();
  if (t == 0) {
    float S = 0.0f, A = 0.0f;
    #pragma unroll
    for (int w = 0; w < 8; ++w) { S += red[w]; A += red[8 + w]; }
    part[2 * bid]     = S;
    part[2 * bid + 1] = A;
  }
}

// ---------------------------------------------------------------------------
// k4: reduce partials + label analytics + finalize (deterministic).
__global__ __launch_bounds__(256) void k4_final(
    const float* __restrict__ part, int G,
    const int* __restrict__ LC, const float* __restrict__ plsum,
    float* __restrict__ out, int B) {
  __shared__ float sl[256], sa[256];
  __shared__ float fin[3];
  int t = threadIdx.x;
  float s = 0.0f, a = 0.0f;
  for (int i = t; i < G; i += 256) {
    s += part[2 * i];
    a += part[2 * i + 1];
  }
  sl[t] = s; sa[t] = a;
  __syncthreads();
  for (int o = 128; o; o >>= 1) {
    if (t < o) { sl[t] += sl[t + o]; sa[t] += sa[t + o]; }
    __syncthreads();
  }
  // label analytics in wave 0 (t < 64)
  if (t < 64) {
    int   c  = LC[t];
    float cf = (float)c;
    float pc = cf * (cf - 1.0f);
    float tr = ((c >= 2) && (c < B)) ? cf * (float)(B - c) : 0.0f;
    float ps = plsum[t];
    pc = wave_reduce_sum(pc);
    tr = wave_reduce_sum(tr);
    ps = wave_reduce_sum(ps);
    if (t == 0) { fin[0] = pc; fin[1] = tr; fin[2] = ps; }
  }
  __syncthreads();
  if (t == 0) {
    float PC = fin[0], TR = fin[1], PS = fin[2];
    float den = fmaxf(TR, 1.0f);
    out[0] = sl[0] / den;                                   // loss
    out[1] = sa[0];                                         // num_active
    out[2] = TR;                                            // total_triplets
    out[3] = sa[0] / den;                                   // active_ratio
    out[4] = (PC > 0.0f) ? PS / fmaxf(PC, 1.0f) : 0.0f;     // mean_distance
  }
}

extern "C" void kernel_launch(void* const* d_in, const int* in_sizes, int n_in,
                              void* d_out, int out_size, void* d_ws, size_t ws_size,
                              hipStream_t stream) {
  const float* emb = (const float*)d_in[0];
  const int*   lab = (const int*)d_in[1];
  int B = in_sizes[1];

  int T2 = B / NT2;
  int ntile = T2 * (T2 + 1) / 2;   // 528 at B=4096

  // ws: bfe (B*D ushort) | sq[B] | vv[B] | hpm[B] | LC[NL](int) | plsum[NL] | part[2*ntile]
  unsigned short* bfe = (unsigned short*)d_ws;
  float* sq    = (float*)(bfe + (size_t)B * D);
  float* vv    = sq + B;
  float* hpm   = vv + B;
  int*   LC    = (int*)(hpm + B);
  float* plsum = (float*)(LC + NL);
  float* part  = plsum + NL;

  kA<<<NL + B / 4, 256, 0, stream>>>(emb, lab, bfe, sq, vv, hpm, LC, plsum, B);
  k3_neg<<<ntile, 512, 0, stream>>>(bfe, lab, sq, vv, hpm, part, B);
  k4_final<<<1, 256, 0, stream>>>(part, ntile, LC, plsum, (float*)d_out, B);
}